// Round 6
// baseline (216.945 us; speedup 1.0000x reference)
//
#include <hip/hip_runtime.h>
#include <hip/hip_bf16.h>

// VectorQuantizer: x [32768 x 64] fp32, e [64 x 1024] fp32.
// d_out = [out (2097152 f32) = x + (q-x), loss = 1.25*mean((q-x)^2)].
//
// R20 = R18's main geometry (1024 blocks x 512 thr, L2-resident linear fp16
// codebook, quarter-split scan, ~12 KB LDS -> 4 blocks/CU, 32 waves/CU)
// RECOMBINED with R19's ticket-free epilogue (plain parts store + separate
// tiny vq_loss dispatch). Evidence: R19 confirmed agent-scope acquire/release
// = full L2 writeback/invalidate (removing it: main 58->43us); R18's 163us
// was that mechanism at 1024 blocks (54 MB WRITE_SIZE), NOT the L2-direct
// scan, whose addressing/correctness R18 validated (absmax 0.0, dense
// 64B-per-code loads, ~7.4us aggregate L2 traffic). This removes the 128 KB
// LDS staging drain and the 1-block/CU occupancy cap that R19's counters
// showed as the residual bottleneck (all pipes <35% busy, dur ~2.9x VALU).
// Scan core, top-3 quarter merge, light (2-candidate exact rescore) and
// heavy (full rescore) paths, epilogue: verbatim from R18 (absmax 0).
// vq_loss replicates R18's final reduction order bit-for-bit.

#define NROWS 32768
#define DDIM  64
#define KCODE 1024
#define NELEM (NROWS * DDIM)
#define MARGIN 4e-3f
#define GRID_MAIN 1024       // 32 rows/block, 512 threads, ~12 KB LDS
#define TPB 512

typedef __attribute__((ext_vector_type(8))) _Float16 f16x8;
typedef __attribute__((ext_vector_type(4))) float f32x4;

static __device__ __forceinline__ unsigned short f2h(float v) {
    _Float16 h = (_Float16)v;
    unsigned short b;
    __builtin_memcpy(&b, &h, 2);
    return b;
}

// ---------------------------------------------------------------------------
// prep (64 blocks x 256): per block 16 codes. se[k] exact fp32 (ascending-d
// fmaf — must match the rescore paths), eT[k][d] fp32, ehL[k][d] fp16 LINEAR
// (B-fragments are read via per-lane global loads; 64 B per code per k-slot).
__global__ void vq_prep(const float* __restrict__ e,
                        float* __restrict__ se,
                        float* __restrict__ eT,
                        unsigned short* __restrict__ ehL,
                        int* __restrict__ ctrl) {
    __shared__ float tile[64][17];
    const int t = threadIdx.x;
    const int k0 = blockIdx.x * 16;
    if (blockIdx.x == 0 && t < 4) ctrl[t] = 0;
    #pragma unroll
    for (int i = 0; i < 4; ++i) {
        int idx = i * 256 + t;
        int d = idx >> 4, kk = idx & 15;
        tile[d][kk] = e[d * KCODE + k0 + kk];
    }
    __syncthreads();
    if (t < 16) {
        float s = 0.f;
        #pragma unroll
        for (int d = 0; d < 64; ++d) { float v = tile[d][t]; s = fmaf(v, v, s); }
        se[k0 + t] = s;
    }
    const int kk = t >> 4;            // code 0..15 within block
    const int dg = (t & 15) * 4;      // dim group (4 elems)
    const int kg = k0 + kk;
    float v0 = tile[dg + 0][kk], v1 = tile[dg + 1][kk];
    float v2 = tile[dg + 2][kk], v3 = tile[dg + 3][kk];
    *(float4*)&eT[(size_t)kg * 64 + dg] = make_float4(v0, v1, v2, v3);
    *(ushort4*)&ehL[(size_t)kg * 64 + dg] =
        make_ushort4(f2h(v0), f2h(v1), f2h(v2), f2h(v3));
}

// ---------------------------------------------------------------------------
__launch_bounds__(TPB, 8)
__global__ void vq_main(const float* __restrict__ x,
                        const float* __restrict__ se,
                        const float* __restrict__ eT,
                        const unsigned short* __restrict__ ehL,
                        float* __restrict__ out,
                        float* __restrict__ parts) {
    __shared__ float sse[KCODE];                 // 4 KB (exact fp32 se copy)
    __shared__ float wsum[2];
    __shared__ float xs[64];                     // heavy rescore: current row
    __shared__ float cb[512];                    // heavy reduction
    __shared__ int   ci[512];
    __shared__ float hv1[4][32], hv2[4][32], hv3[4][32];   // per-quarter top-3
    __shared__ int   hi1[4][32], hi2[4][32];               // per-quarter top-2 idx
    __shared__ int   lightRows[32];              // block-relative light rows
    __shared__ int   lightA[32];                 // light candidate 1 (si)
    __shared__ int   lightB[32];                 // light candidate 2 (si2)
    __shared__ int   heavyRows[32];              // >=3 candidates in margin
    __shared__ int   idxRow[32];                 // per-row final code index
    __shared__ int   sNl, sNh;

    const int t = threadIdx.x;          // 0..511
    const int lane = t & 63;
    const int w = t >> 6;               // wave 0..7
    const int rowGroup = w & 1;         // 2 row-groups x 16 rows = 32 rows
    const int quarter = w >> 1;         // code quarter 0..3
    const int quad = lane >> 4, l15 = lane & 15;
    const int rowBase = blockIdx.x * 32 + rowGroup * 16;

    if (t == 0) { sNl = 0; sNh = 0; }

    // ---- stage se (4 KB) only; codebook stays in L2 ----
    {
        float2 s2 = ((const float2*)se)[t];
        sse[2 * t + 0] = s2.x;
        sse[2 * t + 1] = s2.y;
    }

    // ---- A fragments (fp16 two-term split): row = l15, k = quad*8+ks*32+j ----
    f16x8 ah0, ah1, al0, al1;
    {
        const float4* ap0 = (const float4*)(x + (size_t)(rowBase + l15) * 64 + quad * 8);
        const float4* ap1 = (const float4*)(x + (size_t)(rowBase + l15) * 64 + 32 + quad * 8);
        float4 a0 = ap0[0], a1 = ap0[1], b0 = ap1[0], b1 = ap1[1];
        float av[8] = {a0.x, a0.y, a0.z, a0.w, a1.x, a1.y, a1.z, a1.w};
        float bv[8] = {b0.x, b0.y, b0.z, b0.w, b1.x, b1.y, b1.z, b1.w};
        f16x8 h0, h1, l0, l1;
        #pragma unroll
        for (int j = 0; j < 8; ++j) {
            _Float16 ha = (_Float16)av[j];
            _Float16 hb = (_Float16)bv[j];
            h0[j] = ha;
            h1[j] = hb;
            l0[j] = (_Float16)(av[j] - (float)ha);
            l1[j] = (_Float16)(bv[j] - (float)hb);
        }
        ah0 = h0; ah1 = h1; al0 = l0; al1 = l1;
    }
    __syncthreads();   // sse + counters resident

    // ---- barrier-free quarter-scan: 16 iters x 16 codes, B from L2 ----
    // top-3 values (sb<=sb2<=sb3), top-2 indices (si,si2), earliest-wins ties.
    float sb[4], sb2[4], sb3[4];
    int   si[4], si2[4];
    #pragma unroll
    for (int r = 0; r < 4; ++r) {
        sb[r] = 3.4e38f; sb2[r] = 3.4e38f; sb3[r] = 3.4e38f;
        si[r] = 0; si2[r] = 0;
    }

    const int codeBase = quarter * 256;
    // lane's B pointer: code = codeBase + nt*16 + l15, chunk quad (k-slot 0)
    // and chunk quad+4 (k-slot 1) — same per-lane data as the old LDS path.
    const unsigned short* ehp = ehL + (size_t)(codeBase + l15) * 64 + quad * 8;

    #pragma unroll 4
    for (int nt = 0; nt < 16; ++nt) {
        const int code = codeBase + nt * 16 + l15;
        f16x8 b0 = *(const f16x8*)(ehp + nt * 1024);
        f16x8 b1 = *(const f16x8*)(ehp + nt * 1024 + 32);
        float cse = sse[code];
        f32x4 aA = {0.f, 0.f, 0.f, 0.f}, aB = {0.f, 0.f, 0.f, 0.f};
        aA = __builtin_amdgcn_mfma_f32_16x16x32_f16(ah0, b0, aA, 0, 0, 0);
        aB = __builtin_amdgcn_mfma_f32_16x16x32_f16(ah1, b1, aB, 0, 0, 0);
        aA = __builtin_amdgcn_mfma_f32_16x16x32_f16(al0, b0, aA, 0, 0, 0);
        aB = __builtin_amdgcn_mfma_f32_16x16x32_f16(al1, b1, aB, 0, 0, 0);
        #pragma unroll
        for (int r = 0; r < 4; ++r) {
            float key = fmaf(-2.f, aA[r] + aB[r], cse);   // ~ se - 2*x·eh
            bool lt1 = key < sb[r];               // strict: earliest code wins
            bool lt2 = key < sb2[r];
            bool lt3 = key < sb3[r];
            sb3[r] = lt2 ? sb2[r] : (lt3 ? key : sb3[r]);
            float nsb2 = lt1 ? sb[r] : (lt2 ? key : sb2[r]);
            int   nsi2 = lt1 ? si[r] : (lt2 ? code : si2[r]);
            sb[r]  = lt1 ? key  : sb[r];
            si[r]  = lt1 ? code : si[r];
            sb2[r] = nsb2;
            si2[r] = nsi2;
        }
    }

    // ---- in-wave butterfly top-3 merge over the 16 lanes of each quad ----
    #pragma unroll
    for (int m = 1; m < 16; m <<= 1) {
        #pragma unroll
        for (int r = 0; r < 4; ++r) {
            float b1 = __shfl_xor(sb[r],  m, 64);
            int   i1 = __shfl_xor(si[r],  m, 64);
            float b2 = __shfl_xor(sb2[r], m, 64);
            int   i2 = __shfl_xor(si2[r], m, 64);
            float b3 = __shfl_xor(sb3[r], m, 64);
            // round 1: champion (lexicographic (value, index))
            bool t1 = (b1 < sb[r]) || (b1 == sb[r] && i1 < si[r]);
            float w1 = t1 ? b1 : sb[r];    int wi1 = t1 ? i1 : si[r];
            float l1 = t1 ? sb[r] : b1;    int li1 = t1 ? si[r] : i1;
            float c2 = t1 ? b2 : sb2[r];   int ci2 = t1 ? i2 : si2[r];   // winner side's 2nd
            float c3 = t1 ? b3 : sb3[r];                                  // winner side's 3rd
            float o2 = t1 ? sb2[r] : b2;                                  // loser side's 2nd
            // round 2: second place
            bool t2 = (c2 < l1) || (c2 == l1 && ci2 < li1);
            float w2 = t2 ? c2 : l1;       int wi2 = t2 ? ci2 : li1;
            // third place (value only; used only for the margin test)
            float w3 = t2 ? fminf(l1, c3) : fminf(c2, o2);
            sb[r] = w1; si[r] = wi1; sb2[r] = w2; si2[r] = wi2; sb3[r] = w3;
        }
    }

    // ---- publish this quarter's per-row top-3 to LDS ----
    if (l15 == 0) {
        #pragma unroll
        for (int r = 0; r < 4; ++r) {
            const int rloc = rowGroup * 16 + quad * 4 + r;
            hv1[quarter][rloc] = sb[r];  hi1[quarter][rloc] = si[r];
            hv2[quarter][rloc] = sb2[r]; hi2[quarter][rloc] = si2[r];
            hv3[quarter][rloc] = sb3[r];
        }
    }
    __syncthreads();   // all quarters published

    // ---- merge quarters per row + classify (light/heavy); same lex merge ----
    if (t < 32) {
        float m1[3], mv2[3], m3[3];   // staging for tree merge results
        int   mi1[3], mi2[3];
        // merge (q0,q1) -> slot 0 ; (q2,q3) -> slot 1 ; (slot0,slot1) -> slot 2
        #pragma unroll
        for (int s = 0; s < 3; ++s) {
            float a1, a2, a3, b1, b2, b3;
            int ai1, ai2, bi1, bi2;
            if (s < 2) {
                a1 = hv1[2*s][t];   ai1 = hi1[2*s][t];
                a2 = hv2[2*s][t];   ai2 = hi2[2*s][t];
                a3 = hv3[2*s][t];
                b1 = hv1[2*s+1][t]; bi1 = hi1[2*s+1][t];
                b2 = hv2[2*s+1][t]; bi2 = hi2[2*s+1][t];
                b3 = hv3[2*s+1][t];
            } else {
                a1 = m1[0]; ai1 = mi1[0]; a2 = mv2[0]; ai2 = mi2[0]; a3 = m3[0];
                b1 = m1[1]; bi1 = mi1[1]; b2 = mv2[1]; bi2 = mi2[1]; b3 = m3[1];
            }
            bool t1 = (b1 < a1) || (b1 == a1 && bi1 < ai1);
            float w1 = t1 ? b1 : a1;   int wi1 = t1 ? bi1 : ai1;
            float l1 = t1 ? a1 : b1;   int li1 = t1 ? ai1 : bi1;
            float c2 = t1 ? b2 : a2;   int ci2 = t1 ? bi2 : ai2;
            float c3 = t1 ? b3 : a3;
            float o2 = t1 ? a2 : b2;
            bool t2 = (c2 < l1) || (c2 == l1 && ci2 < li1);
            float w2 = t2 ? c2 : l1;   int wi2 = t2 ? ci2 : li1;
            float w3 = t2 ? fminf(l1, c3) : fminf(c2, o2);
            m1[s] = w1; mi1[s] = wi1; mv2[s] = w2; mi2[s] = wi2; m3[s] = w3;
        }
        const float w1 = m1[2], w2 = mv2[2], w3 = m3[2];
        const int wi1 = mi1[2], wi2 = mi2[2];

        idxRow[t] = wi1;
        if (w2 - w1 < MARGIN) {
            if (w3 - w1 < MARGIN) {
                int p = atomicAdd(&sNh, 1);
                heavyRows[p] = t;
            } else {
                int p = atomicAdd(&sNl, 1);
                lightRows[p] = t;
                lightA[p] = wi1;
                lightB[p] = wi2;
            }
        }
    }
    __syncthreads();   // idxRow + light/heavy lists visible

    // ---- light rows: exact fp32 rescore of the 2 in-margin candidates ----
    // (ascending-d fmaf chains identical to the validated vq_fix math; only
    //  512 B of eT per row; all rows in parallel, 2 threads per row.)
    const int nl = sNl;
    const int nh = sNh;
    if (t < 2 * nl) {
        const int j = t >> 1, s = t & 1;
        const int rloc = lightRows[j];
        const int code = s ? lightB[j] : lightA[j];
        const float4* xr = (const float4*)(x + ((size_t)blockIdx.x * 32 + rloc) * 64);
        const float4* er = (const float4*)(eT + (size_t)code * 64);
        float sx = 0.f, dot = 0.f;
        #pragma unroll
        for (int i4 = 0; i4 < 16; ++i4) {
            float4 xv = xr[i4];
            float4 ev = er[i4];
            sx = fmaf(xv.x, xv.x, sx); sx = fmaf(xv.y, xv.y, sx);
            sx = fmaf(xv.z, xv.z, sx); sx = fmaf(xv.w, xv.w, sx);
            dot = fmaf(xv.x, ev.x, dot); dot = fmaf(xv.y, ev.y, dot);
            dot = fmaf(xv.z, ev.z, dot); dot = fmaf(xv.w, ev.w, dot);
        }
        float dd = (sx + sse[code]) - 2.0f * dot;
        // pair exchange (2j, 2j+1 always in wave 0 since nl <= 32)
        float ddo = __shfl_xor(dd, 1, 64);
        int   ido = __shfl_xor(code, 1, 64);
        bool take = (ddo < dd) || (ddo == dd && ido < code);
        int best = take ? ido : code;
        if (s == 0) idxRow[rloc] = best;
    }

    // ---- heavy rows (>=3 candidates in margin, rare): full block rescore ----
    for (int i = 0; i < nh; ++i) {
        const int rloc = heavyRows[i];
        const size_t grow = (size_t)blockIdx.x * 32 + rloc;
        if (t < 64) xs[t] = x[grow * 64 + t];
        __syncthreads();

        float sx = 0.f;
        #pragma unroll
        for (int d = 0; d < 64; ++d) sx = fmaf(xs[d], xs[d], sx);

        const int k0 = t * 2;
        const float4* e0 = (const float4*)(eT + (size_t)(k0 + 0) * 64);
        const float4* e1 = (const float4*)(eT + (size_t)(k0 + 1) * 64);
        float dot0 = 0.f, dot1 = 0.f;
        #pragma unroll
        for (int i4 = 0; i4 < 16; ++i4) {
            float4 v0 = e0[i4], v1 = e1[i4];
            float xa = xs[4 * i4 + 0], xb = xs[4 * i4 + 1];
            float xc = xs[4 * i4 + 2], xd = xs[4 * i4 + 3];
            dot0 = fmaf(xa, v0.x, dot0); dot0 = fmaf(xb, v0.y, dot0);
            dot0 = fmaf(xc, v0.z, dot0); dot0 = fmaf(xd, v0.w, dot0);
            dot1 = fmaf(xa, v1.x, dot1); dot1 = fmaf(xb, v1.y, dot1);
            dot1 = fmaf(xc, v1.z, dot1); dot1 = fmaf(xd, v1.w, dot1);
        }
        float dd0 = (sx + sse[k0 + 0]) - 2.0f * dot0;
        float dd1 = (sx + sse[k0 + 1]) - 2.0f * dot1;
        float db = dd0; int di = k0;
        if (dd1 < db) { db = dd1; di = k0 + 1; }
        cb[t] = db; ci[t] = di;
        __syncthreads();

        if (t < 64) {
            float B = cb[t]; int I = ci[t];
            #pragma unroll
            for (int s = 64; s < 512; s += 64) {
                float b = cb[t + s]; int i2 = ci[t + s];
                bool take = (b < B) || (b == B && i2 < I);
                B = take ? b : B;
                I = take ? i2 : I;
            }
            #pragma unroll
            for (int m = 1; m < 64; m <<= 1) {
                float ob = __shfl_xor(B, m, 64);
                int   oi = __shfl_xor(I, m, 64);
                bool take = (ob < B) || (ob == B && oi < I);
                B = take ? ob : B;
                I = take ? oi : I;
            }
            if (t == 0) idxRow[rloc] = I;
        }
        __syncthreads();   // idxRow patched; xs/cb/ci safe to reuse
    }
    __syncthreads();       // light idxRow writes visible to epilogue

    // ---- epilogue: waves 0-1, lane -> row rowBase+l15 (w==rowGroup here),
    //      elems [quad*16, quad*16+16); per-row math/order unchanged ----
    if (w < 2) {
        const int myidx = idxRow[w * 16 + l15];
        const float4* qrow = (const float4*)(eT + (size_t)myidx * 64 + quad * 16);
        const float4* xrow = (const float4*)(x + (size_t)(rowBase + l15) * 64 + quad * 16);
        float4* orow = (float4*)(out + (size_t)(rowBase + l15) * 64 + quad * 16);
        float lsum = 0.f;
        #pragma unroll
        for (int i = 0; i < 4; ++i) {
            float4 q = qrow[i];
            float4 xv = xrow[i];
            float4 o;
            float dx;
            dx = q.x - xv.x; o.x = xv.x + dx; lsum = fmaf(dx, dx, lsum);
            dx = q.y - xv.y; o.y = xv.y + dx; lsum = fmaf(dx, dx, lsum);
            dx = q.z - xv.z; o.z = xv.z + dx; lsum = fmaf(dx, dx, lsum);
            dx = q.w - xv.w; o.w = xv.w + dx; lsum = fmaf(dx, dx, lsum);
            orow[i] = o;
        }
        #pragma unroll
        for (int off = 32; off > 0; off >>= 1)
            lsum += __shfl_down(lsum, off, 64);
        if (lane == 0) wsum[w] = lsum;
    }
    __syncthreads();

    // ---- plain store of the block partial (NO agent atomics in hot kernel) ----
    if (t == 0) parts[blockIdx.x] = wsum[0] + wsum[1];
}

// ---------------------------------------------------------------------------
// loss finalize: 1 block x 512, plain loads (dispatch boundary = coherence).
// Reduction order replicates R18's validated last-block sum bit-for-bit.
__launch_bounds__(512)
__global__ void vq_loss(const float* __restrict__ parts,
                        float* __restrict__ out) {
    __shared__ float cb[512];
    const int t = threadIdx.x;
    cb[t] = parts[t] + parts[t + 512];
    __syncthreads();
    if (t < 64) {
        float v = cb[t];
        #pragma unroll
        for (int s = 64; s < 512; s += 64) v += cb[t + s];
        #pragma unroll
        for (int off = 32; off > 0; off >>= 1)
            v += __shfl_down(v, off, 64);
        if (t == 0) {
            float m = v / (float)NELEM;
            out[NELEM] = 0.25f * m + m;
        }
    }
}

// ---------------------------------------------------------------------------
extern "C" void kernel_launch(void* const* d_in, const int* in_sizes, int n_in,
                              void* d_out, int out_size, void* d_ws, size_t ws_size,
                              hipStream_t stream) {
    const float* x = (const float*)d_in[0];
    const float* e = (const float*)d_in[1];
    float* out = (float*)d_out;
    float* ws  = (float*)d_ws;

    // ws layout (float offsets):
    //   [0..15]   ctrl (zeroed by prep; unused)
    //   +64       se   [1024]
    //   +1280     eT   [65536]
    //   +66816    ehL  [65536 ushort = 32768 f]  (linear fp16 codebook)
    //   +165120   parts[1024]
    float* se            = ws + 64;
    float* eT            = ws + 1280;
    unsigned short* ehL  = (unsigned short*)(ws + 66816);
    float* parts         = ws + 165120;

    vq_prep<<<64, 256, 0, stream>>>(e, se, eT, ehL, (int*)ws);
    vq_main<<<GRID_MAIN, TPB, 0, stream>>>(x, se, eT, ehL, out, parts);
    vq_loss<<<1, 512, 0, stream>>>(parts, out);
}

// Round 7
// 142.871 us; speedup vs baseline: 1.5185x; 1.5185x over previous
//
#include <hip/hip_runtime.h>
#include <hip/hip_bf16.h>

// VectorQuantizer: x [32768 x 64] fp32, e [64 x 1024] fp32.
// d_out = [out (2097152 f32) = x + (q-x), loss = 1.25*mean((q-x)^2)].
//
// R21 = R20 with the SPILL fixed. R20's VGPR_Count=32 was impossible for the
// scan's >=44-reg live set (4x f16x8 A-frags=16, b0/b1=8, top-3 state=20):
// __launch_bounds__(512,8) capped VGPR at 64 and the allocator spilled the
// scan state to scratch -> FETCH+WRITE exploded to 126 MB (vs ~25 ideal) and
// main ran 158us. Same mechanism sabotaged R18 (cap 85, VGPR 40, 67 MB).
// The L2-direct codebook itself is sound (~3.7us at L2 BW, absmax 0.0 twice).
// Changes vs R20:
//   1. __launch_bounds__(512, 4): VGPR cap 128 -> no spill (R19 ran the same
//      scan at VGPR 64 cleanly); occupancy still >=16 waves/CU.
//   2. Quarter-merge scalarized (named-scalar MERGE3, no arrays) so nothing
//      can be demoted to scratch (rule: runtime-indexed arrays -> scratch).
// Scan core, top-3 butterfly, light/heavy rescue, epilogue, ticket-free
// parts + separate vq_loss: verbatim from R20/R19 (validated).

#define NROWS 32768
#define DDIM  64
#define KCODE 1024
#define NELEM (NROWS * DDIM)
#define MARGIN 4e-3f
#define GRID_MAIN 1024       // 32 rows/block, 512 threads, ~12 KB LDS
#define TPB 512

typedef __attribute__((ext_vector_type(8))) _Float16 f16x8;
typedef __attribute__((ext_vector_type(4))) float f32x4;

static __device__ __forceinline__ unsigned short f2h(float v) {
    _Float16 h = (_Float16)v;
    unsigned short b;
    __builtin_memcpy(&b, &h, 2);
    return b;
}

// Exact lexicographic merge of two (v1,i1,v2,i2,v3) top-3 partials.
// Identical compare chain to the validated R17/R18 merges.
#define MERGE3(a1,ai1,a2,ai2,a3, b1,bi1,b2,bi2,b3, o1,oi1,o2,oi2,o3) do { \
    bool mt1 = ((b1) < (a1)) || ((b1) == (a1) && (bi1) < (ai1));          \
    float MW1 = mt1 ? (b1) : (a1);  int MWI1 = mt1 ? (bi1) : (ai1);       \
    float ML1 = mt1 ? (a1) : (b1);  int MLI1 = mt1 ? (ai1) : (bi1);       \
    float MC2 = mt1 ? (b2) : (a2);  int MCI2 = mt1 ? (bi2) : (ai2);       \
    float MC3 = mt1 ? (b3) : (a3);                                        \
    float MO2 = mt1 ? (a2) : (b2);                                        \
    bool mt2 = (MC2 < ML1) || (MC2 == ML1 && MCI2 < MLI1);                \
    (o1) = MW1; (oi1) = MWI1;                                             \
    (o2) = mt2 ? MC2 : ML1; (oi2) = mt2 ? MCI2 : MLI1;                    \
    (o3) = mt2 ? fminf(ML1, MC3) : fminf(MC2, MO2);                       \
} while (0)

// ---------------------------------------------------------------------------
// prep (64 blocks x 256): per block 16 codes. se[k] exact fp32 (ascending-d
// fmaf — must match the rescore paths), eT[k][d] fp32, ehL[k][d] fp16 LINEAR
// (B-fragments are read via per-lane global loads; 64 B per code per k-slot).
__global__ void vq_prep(const float* __restrict__ e,
                        float* __restrict__ se,
                        float* __restrict__ eT,
                        unsigned short* __restrict__ ehL,
                        int* __restrict__ ctrl) {
    __shared__ float tile[64][17];
    const int t = threadIdx.x;
    const int k0 = blockIdx.x * 16;
    if (blockIdx.x == 0 && t < 4) ctrl[t] = 0;
    #pragma unroll
    for (int i = 0; i < 4; ++i) {
        int idx = i * 256 + t;
        int d = idx >> 4, kk = idx & 15;
        tile[d][kk] = e[d * KCODE + k0 + kk];
    }
    __syncthreads();
    if (t < 16) {
        float s = 0.f;
        #pragma unroll
        for (int d = 0; d < 64; ++d) { float v = tile[d][t]; s = fmaf(v, v, s); }
        se[k0 + t] = s;
    }
    const int kk = t >> 4;            // code 0..15 within block
    const int dg = (t & 15) * 4;      // dim group (4 elems)
    const int kg = k0 + kk;
    float v0 = tile[dg + 0][kk], v1 = tile[dg + 1][kk];
    float v2 = tile[dg + 2][kk], v3 = tile[dg + 3][kk];
    *(float4*)&eT[(size_t)kg * 64 + dg] = make_float4(v0, v1, v2, v3);
    *(ushort4*)&ehL[(size_t)kg * 64 + dg] =
        make_ushort4(f2h(v0), f2h(v1), f2h(v2), f2h(v3));
}

// ---------------------------------------------------------------------------
__launch_bounds__(TPB, 4)
__global__ void vq_main(const float* __restrict__ x,
                        const float* __restrict__ se,
                        const float* __restrict__ eT,
                        const unsigned short* __restrict__ ehL,
                        float* __restrict__ out,
                        float* __restrict__ parts) {
    __shared__ float sse[KCODE];                 // 4 KB (exact fp32 se copy)
    __shared__ float wsum[2];
    __shared__ float xs[64];                     // heavy rescore: current row
    __shared__ float cb[512];                    // heavy reduction
    __shared__ int   ci[512];
    __shared__ float hv1[4][32], hv2[4][32], hv3[4][32];   // per-quarter top-3
    __shared__ int   hi1[4][32], hi2[4][32];               // per-quarter top-2 idx
    __shared__ int   lightRows[32];              // block-relative light rows
    __shared__ int   lightA[32];                 // light candidate 1 (si)
    __shared__ int   lightB[32];                 // light candidate 2 (si2)
    __shared__ int   heavyRows[32];              // >=3 candidates in margin
    __shared__ int   idxRow[32];                 // per-row final code index
    __shared__ int   sNl, sNh;

    const int t = threadIdx.x;          // 0..511
    const int lane = t & 63;
    const int w = t >> 6;               // wave 0..7
    const int rowGroup = w & 1;         // 2 row-groups x 16 rows = 32 rows
    const int quarter = w >> 1;         // code quarter 0..3
    const int quad = lane >> 4, l15 = lane & 15;
    const int rowBase = blockIdx.x * 32 + rowGroup * 16;

    if (t == 0) { sNl = 0; sNh = 0; }

    // ---- stage se (4 KB) only; codebook stays in L2 ----
    {
        float2 s2 = ((const float2*)se)[t];
        sse[2 * t + 0] = s2.x;
        sse[2 * t + 1] = s2.y;
    }

    // ---- A fragments (fp16 two-term split): row = l15, k = quad*8+ks*32+j ----
    f16x8 ah0, ah1, al0, al1;
    {
        const float4* ap0 = (const float4*)(x + (size_t)(rowBase + l15) * 64 + quad * 8);
        const float4* ap1 = (const float4*)(x + (size_t)(rowBase + l15) * 64 + 32 + quad * 8);
        float4 a0 = ap0[0], a1 = ap0[1], b0 = ap1[0], b1 = ap1[1];
        float av[8] = {a0.x, a0.y, a0.z, a0.w, a1.x, a1.y, a1.z, a1.w};
        float bv[8] = {b0.x, b0.y, b0.z, b0.w, b1.x, b1.y, b1.z, b1.w};
        f16x8 h0, h1, l0, l1;
        #pragma unroll
        for (int j = 0; j < 8; ++j) {
            _Float16 ha = (_Float16)av[j];
            _Float16 hb = (_Float16)bv[j];
            h0[j] = ha;
            h1[j] = hb;
            l0[j] = (_Float16)(av[j] - (float)ha);
            l1[j] = (_Float16)(bv[j] - (float)hb);
        }
        ah0 = h0; ah1 = h1; al0 = l0; al1 = l1;
    }
    __syncthreads();   // sse + counters resident

    // ---- barrier-free quarter-scan: 16 iters x 16 codes, B from L2 ----
    // top-3 values (sb<=sb2<=sb3), top-2 indices (si,si2), earliest-wins ties.
    float sb[4], sb2[4], sb3[4];
    int   si[4], si2[4];
    #pragma unroll
    for (int r = 0; r < 4; ++r) {
        sb[r] = 3.4e38f; sb2[r] = 3.4e38f; sb3[r] = 3.4e38f;
        si[r] = 0; si2[r] = 0;
    }

    const int codeBase = quarter * 256;
    // lane's B pointer: code = codeBase + nt*16 + l15, chunk quad (k-slot 0)
    // and chunk quad+4 (k-slot 1) — same per-lane data as the old LDS path.
    const unsigned short* ehp = ehL + (size_t)(codeBase + l15) * 64 + quad * 8;

    #pragma unroll 4
    for (int nt = 0; nt < 16; ++nt) {
        const int code = codeBase + nt * 16 + l15;
        f16x8 b0 = *(const f16x8*)(ehp + nt * 1024);
        f16x8 b1 = *(const f16x8*)(ehp + nt * 1024 + 32);
        float cse = sse[code];
        f32x4 aA = {0.f, 0.f, 0.f, 0.f}, aB = {0.f, 0.f, 0.f, 0.f};
        aA = __builtin_amdgcn_mfma_f32_16x16x32_f16(ah0, b0, aA, 0, 0, 0);
        aB = __builtin_amdgcn_mfma_f32_16x16x32_f16(ah1, b1, aB, 0, 0, 0);
        aA = __builtin_amdgcn_mfma_f32_16x16x32_f16(al0, b0, aA, 0, 0, 0);
        aB = __builtin_amdgcn_mfma_f32_16x16x32_f16(al1, b1, aB, 0, 0, 0);
        #pragma unroll
        for (int r = 0; r < 4; ++r) {
            float key = fmaf(-2.f, aA[r] + aB[r], cse);   // ~ se - 2*x·eh
            bool lt1 = key < sb[r];               // strict: earliest code wins
            bool lt2 = key < sb2[r];
            bool lt3 = key < sb3[r];
            sb3[r] = lt2 ? sb2[r] : (lt3 ? key : sb3[r]);
            float nsb2 = lt1 ? sb[r] : (lt2 ? key : sb2[r]);
            int   nsi2 = lt1 ? si[r] : (lt2 ? code : si2[r]);
            sb[r]  = lt1 ? key  : sb[r];
            si[r]  = lt1 ? code : si[r];
            sb2[r] = nsb2;
            si2[r] = nsi2;
        }
    }

    // ---- in-wave butterfly top-3 merge over the 16 lanes of each quad ----
    #pragma unroll
    for (int m = 1; m < 16; m <<= 1) {
        #pragma unroll
        for (int r = 0; r < 4; ++r) {
            float b1 = __shfl_xor(sb[r],  m, 64);
            int   i1 = __shfl_xor(si[r],  m, 64);
            float b2 = __shfl_xor(sb2[r], m, 64);
            int   i2 = __shfl_xor(si2[r], m, 64);
            float b3 = __shfl_xor(sb3[r], m, 64);
            float n1, n2, n3; int ni1, ni2;
            MERGE3(sb[r], si[r], sb2[r], si2[r], sb3[r],
                   b1, i1, b2, i2, b3,
                   n1, ni1, n2, ni2, n3);
            sb[r] = n1; si[r] = ni1; sb2[r] = n2; si2[r] = ni2; sb3[r] = n3;
        }
    }

    // ---- publish this quarter's per-row top-3 to LDS ----
    if (l15 == 0) {
        #pragma unroll
        for (int r = 0; r < 4; ++r) {
            const int rloc = rowGroup * 16 + quad * 4 + r;
            hv1[quarter][rloc] = sb[r];  hi1[quarter][rloc] = si[r];
            hv2[quarter][rloc] = sb2[r]; hi2[quarter][rloc] = si2[r];
            hv3[quarter][rloc] = sb3[r];
        }
    }
    __syncthreads();   // all quarters published

    // ---- merge quarters per row + classify (light/heavy); scalar tree ----
    if (t < 32) {
        float A1, A2, A3, B1, B2, B3, w1, w2, w3;
        int Ai1, Ai2, Bi1, Bi2, wi1, wi2;
        MERGE3(hv1[0][t], hi1[0][t], hv2[0][t], hi2[0][t], hv3[0][t],
               hv1[1][t], hi1[1][t], hv2[1][t], hi2[1][t], hv3[1][t],
               A1, Ai1, A2, Ai2, A3);
        MERGE3(hv1[2][t], hi1[2][t], hv2[2][t], hi2[2][t], hv3[2][t],
               hv1[3][t], hi1[3][t], hv2[3][t], hi2[3][t], hv3[3][t],
               B1, Bi1, B2, Bi2, B3);
        MERGE3(A1, Ai1, A2, Ai2, A3,
               B1, Bi1, B2, Bi2, B3,
               w1, wi1, w2, wi2, w3);

        idxRow[t] = wi1;
        if (w2 - w1 < MARGIN) {
            if (w3 - w1 < MARGIN) {
                int p = atomicAdd(&sNh, 1);
                heavyRows[p] = t;
            } else {
                int p = atomicAdd(&sNl, 1);
                lightRows[p] = t;
                lightA[p] = wi1;
                lightB[p] = wi2;
            }
        }
    }
    __syncthreads();   // idxRow + light/heavy lists visible

    // ---- light rows: exact fp32 rescore of the 2 in-margin candidates ----
    // (ascending-d fmaf chains identical to the validated vq_fix math; only
    //  512 B of eT per row; all rows in parallel, 2 threads per row.)
    const int nl = sNl;
    const int nh = sNh;
    if (t < 2 * nl) {
        const int j = t >> 1, s = t & 1;
        const int rloc = lightRows[j];
        const int code = s ? lightB[j] : lightA[j];
        const float4* xr = (const float4*)(x + ((size_t)blockIdx.x * 32 + rloc) * 64);
        const float4* er = (const float4*)(eT + (size_t)code * 64);
        float sx = 0.f, dot = 0.f;
        #pragma unroll
        for (int i4 = 0; i4 < 16; ++i4) {
            float4 xv = xr[i4];
            float4 ev = er[i4];
            sx = fmaf(xv.x, xv.x, sx); sx = fmaf(xv.y, xv.y, sx);
            sx = fmaf(xv.z, xv.z, sx); sx = fmaf(xv.w, xv.w, sx);
            dot = fmaf(xv.x, ev.x, dot); dot = fmaf(xv.y, ev.y, dot);
            dot = fmaf(xv.z, ev.z, dot); dot = fmaf(xv.w, ev.w, dot);
        }
        float dd = (sx + sse[code]) - 2.0f * dot;
        // pair exchange (2j, 2j+1 always in wave 0 since nl <= 32)
        float ddo = __shfl_xor(dd, 1, 64);
        int   ido = __shfl_xor(code, 1, 64);
        bool take = (ddo < dd) || (ddo == dd && ido < code);
        int best = take ? ido : code;
        if (s == 0) idxRow[rloc] = best;
    }

    // ---- heavy rows (>=3 candidates in margin, rare): full block rescore ----
    for (int i = 0; i < nh; ++i) {
        const int rloc = heavyRows[i];
        const size_t grow = (size_t)blockIdx.x * 32 + rloc;
        if (t < 64) xs[t] = x[grow * 64 + t];
        __syncthreads();

        float sx = 0.f;
        #pragma unroll
        for (int d = 0; d < 64; ++d) sx = fmaf(xs[d], xs[d], sx);

        const int k0 = t * 2;
        const float4* e0 = (const float4*)(eT + (size_t)(k0 + 0) * 64);
        const float4* e1 = (const float4*)(eT + (size_t)(k0 + 1) * 64);
        float dot0 = 0.f, dot1 = 0.f;
        #pragma unroll
        for (int i4 = 0; i4 < 16; ++i4) {
            float4 v0 = e0[i4], v1 = e1[i4];
            float xa = xs[4 * i4 + 0], xb = xs[4 * i4 + 1];
            float xc = xs[4 * i4 + 2], xd = xs[4 * i4 + 3];
            dot0 = fmaf(xa, v0.x, dot0); dot0 = fmaf(xb, v0.y, dot0);
            dot0 = fmaf(xc, v0.z, dot0); dot0 = fmaf(xd, v0.w, dot0);
            dot1 = fmaf(xa, v1.x, dot1); dot1 = fmaf(xb, v1.y, dot1);
            dot1 = fmaf(xc, v1.z, dot1); dot1 = fmaf(xd, v1.w, dot1);
        }
        float dd0 = (sx + sse[k0 + 0]) - 2.0f * dot0;
        float dd1 = (sx + sse[k0 + 1]) - 2.0f * dot1;
        float db = dd0; int di = k0;
        if (dd1 < db) { db = dd1; di = k0 + 1; }
        cb[t] = db; ci[t] = di;
        __syncthreads();

        if (t < 64) {
            float B = cb[t]; int I = ci[t];
            #pragma unroll
            for (int s = 64; s < 512; s += 64) {
                float b = cb[t + s]; int i2 = ci[t + s];
                bool take = (b < B) || (b == B && i2 < I);
                B = take ? b : B;
                I = take ? i2 : I;
            }
            #pragma unroll
            for (int m = 1; m < 64; m <<= 1) {
                float ob = __shfl_xor(B, m, 64);
                int   oi = __shfl_xor(I, m, 64);
                bool take = (ob < B) || (ob == B && oi < I);
                B = take ? ob : B;
                I = take ? oi : I;
            }
            if (t == 0) idxRow[rloc] = I;
        }
        __syncthreads();   // idxRow patched; xs/cb/ci safe to reuse
    }
    __syncthreads();       // light idxRow writes visible to epilogue

    // ---- epilogue: waves 0-1, lane -> row rowBase+l15 (w==rowGroup here),
    //      elems [quad*16, quad*16+16); per-row math/order unchanged ----
    if (w < 2) {
        const int myidx = idxRow[w * 16 + l15];
        const float4* qrow = (const float4*)(eT + (size_t)myidx * 64 + quad * 16);
        const float4* xrow = (const float4*)(x + (size_t)(rowBase + l15) * 64 + quad * 16);
        float4* orow = (float4*)(out + (size_t)(rowBase + l15) * 64 + quad * 16);
        float lsum = 0.f;
        #pragma unroll
        for (int i = 0; i < 4; ++i) {
            float4 q = qrow[i];
            float4 xv = xrow[i];
            float4 o;
            float dx;
            dx = q.x - xv.x; o.x = xv.x + dx; lsum = fmaf(dx, dx, lsum);
            dx = q.y - xv.y; o.y = xv.y + dx; lsum = fmaf(dx, dx, lsum);
            dx = q.z - xv.z; o.z = xv.z + dx; lsum = fmaf(dx, dx, lsum);
            dx = q.w - xv.w; o.w = xv.w + dx; lsum = fmaf(dx, dx, lsum);
            orow[i] = o;
        }
        #pragma unroll
        for (int off = 32; off > 0; off >>= 1)
            lsum += __shfl_down(lsum, off, 64);
        if (lane == 0) wsum[w] = lsum;
    }
    __syncthreads();

    // ---- plain store of the block partial (NO agent atomics in hot kernel) ----
    if (t == 0) parts[blockIdx.x] = wsum[0] + wsum[1];
}

// ---------------------------------------------------------------------------
// loss finalize: 1 block x 512, plain loads (dispatch boundary = coherence).
// Reduction order replicates R20's validated sum bit-for-bit.
__launch_bounds__(512)
__global__ void vq_loss(const float* __restrict__ parts,
                        float* __restrict__ out) {
    __shared__ float cb[512];
    const int t = threadIdx.x;
    cb[t] = parts[t] + parts[t + 512];
    __syncthreads();
    if (t < 64) {
        float v = cb[t];
        #pragma unroll
        for (int s = 64; s < 512; s += 64) v += cb[t + s];
        #pragma unroll
        for (int off = 32; off > 0; off >>= 1)
            v += __shfl_down(v, off, 64);
        if (t == 0) {
            float m = v / (float)NELEM;
            out[NELEM] = 0.25f * m + m;
        }
    }
}

// ---------------------------------------------------------------------------
extern "C" void kernel_launch(void* const* d_in, const int* in_sizes, int n_in,
                              void* d_out, int out_size, void* d_ws, size_t ws_size,
                              hipStream_t stream) {
    const float* x = (const float*)d_in[0];
    const float* e = (const float*)d_in[1];
    float* out = (float*)d_out;
    float* ws  = (float*)d_ws;

    // ws layout (float offsets):
    //   [0..15]   ctrl (zeroed by prep; unused)
    //   +64       se   [1024]
    //   +1280     eT   [65536]
    //   +66816    ehL  [65536 ushort = 32768 f]  (linear fp16 codebook)
    //   +165120   parts[1024]
    float* se            = ws + 64;
    float* eT            = ws + 1280;
    unsigned short* ehL  = (unsigned short*)(ws + 66816);
    float* parts         = ws + 165120;

    vq_prep<<<64, 256, 0, stream>>>(e, se, eT, ehL, (int*)ws);
    vq_main<<<GRID_MAIN, TPB, 0, stream>>>(x, se, eT, ehL, out, parts);
    vq_loss<<<1, 512, 0, stream>>>(parts, out);
}

// Round 8
// 136.670 us; speedup vs baseline: 1.5874x; 1.0454x over previous
//
#include <hip/hip_runtime.h>
#include <hip/hip_bf16.h>

// VectorQuantizer: x [32768 x 64] fp32, e [64 x 1024] fp32.
// d_out = [out (2097152 f32) = x + (q-x), loss = 1.25*mean((q-x)^2)].
//
// R22 = R21 with the REMAINING spill removed. Dose-response across R19-R21:
// WRITE_SIZE (scratch write-through) tracks duration 1:1 — 84MB/158us (cap
// 64), 42MB/85us (allocator landed 64), 8.2MB/43us (no spill). R21 still
// spilled because the L2-direct scan software-pipelines GLOBAL loads:
// unroll 4 holds 8x16B load destinations (32 VGPR) on top of the ~44-reg
// persistent live set; at 64 VGPR the overflow went to scratch.
// Changes vs R21 (both target the same mechanism):
//   1. __launch_bounds__(512) with NO min-waves arg -> VGPR cap 256; the
//      allocator can land at the ~88-112 the loop actually needs (still
//      4-5 waves/SIMD = ~20 waves/CU, more TLP than R19's 16).
//   2. #pragma unroll 2 on the scan loop -> 4 loads in flight (16 dest
//      VGPRs), trimming peak pressure.
// Scan core, top-3 butterfly + MERGE3 trees, light/heavy rescue, epilogue,
// ticket-free parts + separate vq_loss: verbatim from R21 (absmax 0.0).

#define NROWS 32768
#define DDIM  64
#define KCODE 1024
#define NELEM (NROWS * DDIM)
#define MARGIN 4e-3f
#define GRID_MAIN 1024       // 32 rows/block, 512 threads, ~12 KB LDS
#define TPB 512

typedef __attribute__((ext_vector_type(8))) _Float16 f16x8;
typedef __attribute__((ext_vector_type(4))) float f32x4;

static __device__ __forceinline__ unsigned short f2h(float v) {
    _Float16 h = (_Float16)v;
    unsigned short b;
    __builtin_memcpy(&b, &h, 2);
    return b;
}

// Exact lexicographic merge of two (v1,i1,v2,i2,v3) top-3 partials.
// Identical compare chain to the validated R17/R18 merges.
#define MERGE3(a1,ai1,a2,ai2,a3, b1,bi1,b2,bi2,b3, o1,oi1,o2,oi2,o3) do { \
    bool mt1 = ((b1) < (a1)) || ((b1) == (a1) && (bi1) < (ai1));          \
    float MW1 = mt1 ? (b1) : (a1);  int MWI1 = mt1 ? (bi1) : (ai1);       \
    float ML1 = mt1 ? (a1) : (b1);  int MLI1 = mt1 ? (ai1) : (bi1);       \
    float MC2 = mt1 ? (b2) : (a2);  int MCI2 = mt1 ? (bi2) : (ai2);       \
    float MC3 = mt1 ? (b3) : (a3);                                        \
    float MO2 = mt1 ? (a2) : (b2);                                        \
    bool mt2 = (MC2 < ML1) || (MC2 == ML1 && MCI2 < MLI1);                \
    (o1) = MW1; (oi1) = MWI1;                                             \
    (o2) = mt2 ? MC2 : ML1; (oi2) = mt2 ? MCI2 : MLI1;                    \
    (o3) = mt2 ? fminf(ML1, MC3) : fminf(MC2, MO2);                       \
} while (0)

// ---------------------------------------------------------------------------
// prep (64 blocks x 256): per block 16 codes. se[k] exact fp32 (ascending-d
// fmaf — must match the rescore paths), eT[k][d] fp32, ehL[k][d] fp16 LINEAR
// (B-fragments are read via per-lane global loads; 64 B per code per k-slot).
__global__ void vq_prep(const float* __restrict__ e,
                        float* __restrict__ se,
                        float* __restrict__ eT,
                        unsigned short* __restrict__ ehL,
                        int* __restrict__ ctrl) {
    __shared__ float tile[64][17];
    const int t = threadIdx.x;
    const int k0 = blockIdx.x * 16;
    if (blockIdx.x == 0 && t < 4) ctrl[t] = 0;
    #pragma unroll
    for (int i = 0; i < 4; ++i) {
        int idx = i * 256 + t;
        int d = idx >> 4, kk = idx & 15;
        tile[d][kk] = e[d * KCODE + k0 + kk];
    }
    __syncthreads();
    if (t < 16) {
        float s = 0.f;
        #pragma unroll
        for (int d = 0; d < 64; ++d) { float v = tile[d][t]; s = fmaf(v, v, s); }
        se[k0 + t] = s;
    }
    const int kk = t >> 4;            // code 0..15 within block
    const int dg = (t & 15) * 4;      // dim group (4 elems)
    const int kg = k0 + kk;
    float v0 = tile[dg + 0][kk], v1 = tile[dg + 1][kk];
    float v2 = tile[dg + 2][kk], v3 = tile[dg + 3][kk];
    *(float4*)&eT[(size_t)kg * 64 + dg] = make_float4(v0, v1, v2, v3);
    *(ushort4*)&ehL[(size_t)kg * 64 + dg] =
        make_ushort4(f2h(v0), f2h(v1), f2h(v2), f2h(v3));
}

// ---------------------------------------------------------------------------
__launch_bounds__(TPB)
__global__ void vq_main(const float* __restrict__ x,
                        const float* __restrict__ se,
                        const float* __restrict__ eT,
                        const unsigned short* __restrict__ ehL,
                        float* __restrict__ out,
                        float* __restrict__ parts) {
    __shared__ float sse[KCODE];                 // 4 KB (exact fp32 se copy)
    __shared__ float wsum[2];
    __shared__ float xs[64];                     // heavy rescore: current row
    __shared__ float cb[512];                    // heavy reduction
    __shared__ int   ci[512];
    __shared__ float hv1[4][32], hv2[4][32], hv3[4][32];   // per-quarter top-3
    __shared__ int   hi1[4][32], hi2[4][32];               // per-quarter top-2 idx
    __shared__ int   lightRows[32];              // block-relative light rows
    __shared__ int   lightA[32];                 // light candidate 1 (si)
    __shared__ int   lightB[32];                 // light candidate 2 (si2)
    __shared__ int   heavyRows[32];              // >=3 candidates in margin
    __shared__ int   idxRow[32];                 // per-row final code index
    __shared__ int   sNl, sNh;

    const int t = threadIdx.x;          // 0..511
    const int lane = t & 63;
    const int w = t >> 6;               // wave 0..7
    const int rowGroup = w & 1;         // 2 row-groups x 16 rows = 32 rows
    const int quarter = w >> 1;         // code quarter 0..3
    const int quad = lane >> 4, l15 = lane & 15;
    const int rowBase = blockIdx.x * 32 + rowGroup * 16;

    if (t == 0) { sNl = 0; sNh = 0; }

    // ---- stage se (4 KB) only; codebook stays in L2 ----
    {
        float2 s2 = ((const float2*)se)[t];
        sse[2 * t + 0] = s2.x;
        sse[2 * t + 1] = s2.y;
    }

    // ---- A fragments (fp16 two-term split): row = l15, k = quad*8+ks*32+j ----
    f16x8 ah0, ah1, al0, al1;
    {
        const float4* ap0 = (const float4*)(x + (size_t)(rowBase + l15) * 64 + quad * 8);
        const float4* ap1 = (const float4*)(x + (size_t)(rowBase + l15) * 64 + 32 + quad * 8);
        float4 a0 = ap0[0], a1 = ap0[1], b0 = ap1[0], b1 = ap1[1];
        float av[8] = {a0.x, a0.y, a0.z, a0.w, a1.x, a1.y, a1.z, a1.w};
        float bv[8] = {b0.x, b0.y, b0.z, b0.w, b1.x, b1.y, b1.z, b1.w};
        f16x8 h0, h1, l0, l1;
        #pragma unroll
        for (int j = 0; j < 8; ++j) {
            _Float16 ha = (_Float16)av[j];
            _Float16 hb = (_Float16)bv[j];
            h0[j] = ha;
            h1[j] = hb;
            l0[j] = (_Float16)(av[j] - (float)ha);
            l1[j] = (_Float16)(bv[j] - (float)hb);
        }
        ah0 = h0; ah1 = h1; al0 = l0; al1 = l1;
    }
    __syncthreads();   // sse + counters resident

    // ---- barrier-free quarter-scan: 16 iters x 16 codes, B from L2 ----
    // top-3 values (sb<=sb2<=sb3), top-2 indices (si,si2), earliest-wins ties.
    float sb[4], sb2[4], sb3[4];
    int   si[4], si2[4];
    #pragma unroll
    for (int r = 0; r < 4; ++r) {
        sb[r] = 3.4e38f; sb2[r] = 3.4e38f; sb3[r] = 3.4e38f;
        si[r] = 0; si2[r] = 0;
    }

    const int codeBase = quarter * 256;
    // lane's B pointer: code = codeBase + nt*16 + l15, chunk quad (k-slot 0)
    // and chunk quad+4 (k-slot 1) — same per-lane data as the old LDS path.
    const unsigned short* ehp = ehL + (size_t)(codeBase + l15) * 64 + quad * 8;

    #pragma unroll 2
    for (int nt = 0; nt < 16; ++nt) {
        const int code = codeBase + nt * 16 + l15;
        f16x8 b0 = *(const f16x8*)(ehp + nt * 1024);
        f16x8 b1 = *(const f16x8*)(ehp + nt * 1024 + 32);
        float cse = sse[code];
        f32x4 aA = {0.f, 0.f, 0.f, 0.f}, aB = {0.f, 0.f, 0.f, 0.f};
        aA = __builtin_amdgcn_mfma_f32_16x16x32_f16(ah0, b0, aA, 0, 0, 0);
        aB = __builtin_amdgcn_mfma_f32_16x16x32_f16(ah1, b1, aB, 0, 0, 0);
        aA = __builtin_amdgcn_mfma_f32_16x16x32_f16(al0, b0, aA, 0, 0, 0);
        aB = __builtin_amdgcn_mfma_f32_16x16x32_f16(al1, b1, aB, 0, 0, 0);
        #pragma unroll
        for (int r = 0; r < 4; ++r) {
            float key = fmaf(-2.f, aA[r] + aB[r], cse);   // ~ se - 2*x·eh
            bool lt1 = key < sb[r];               // strict: earliest code wins
            bool lt2 = key < sb2[r];
            bool lt3 = key < sb3[r];
            sb3[r] = lt2 ? sb2[r] : (lt3 ? key : sb3[r]);
            float nsb2 = lt1 ? sb[r] : (lt2 ? key : sb2[r]);
            int   nsi2 = lt1 ? si[r] : (lt2 ? code : si2[r]);
            sb[r]  = lt1 ? key  : sb[r];
            si[r]  = lt1 ? code : si[r];
            sb2[r] = nsb2;
            si2[r] = nsi2;
        }
    }

    // ---- in-wave butterfly top-3 merge over the 16 lanes of each quad ----
    #pragma unroll
    for (int m = 1; m < 16; m <<= 1) {
        #pragma unroll
        for (int r = 0; r < 4; ++r) {
            float b1 = __shfl_xor(sb[r],  m, 64);
            int   i1 = __shfl_xor(si[r],  m, 64);
            float b2 = __shfl_xor(sb2[r], m, 64);
            int   i2 = __shfl_xor(si2[r], m, 64);
            float b3 = __shfl_xor(sb3[r], m, 64);
            float n1, n2, n3; int ni1, ni2;
            MERGE3(sb[r], si[r], sb2[r], si2[r], sb3[r],
                   b1, i1, b2, i2, b3,
                   n1, ni1, n2, ni2, n3);
            sb[r] = n1; si[r] = ni1; sb2[r] = n2; si2[r] = ni2; sb3[r] = n3;
        }
    }

    // ---- publish this quarter's per-row top-3 to LDS ----
    if (l15 == 0) {
        #pragma unroll
        for (int r = 0; r < 4; ++r) {
            const int rloc = rowGroup * 16 + quad * 4 + r;
            hv1[quarter][rloc] = sb[r];  hi1[quarter][rloc] = si[r];
            hv2[quarter][rloc] = sb2[r]; hi2[quarter][rloc] = si2[r];
            hv3[quarter][rloc] = sb3[r];
        }
    }
    __syncthreads();   // all quarters published

    // ---- merge quarters per row + classify (light/heavy); scalar tree ----
    if (t < 32) {
        float A1, A2, A3, B1, B2, B3, w1, w2, w3;
        int Ai1, Ai2, Bi1, Bi2, wi1, wi2;
        MERGE3(hv1[0][t], hi1[0][t], hv2[0][t], hi2[0][t], hv3[0][t],
               hv1[1][t], hi1[1][t], hv2[1][t], hi2[1][t], hv3[1][t],
               A1, Ai1, A2, Ai2, A3);
        MERGE3(hv1[2][t], hi1[2][t], hv2[2][t], hi2[2][t], hv3[2][t],
               hv1[3][t], hi1[3][t], hv2[3][t], hi2[3][t], hv3[3][t],
               B1, Bi1, B2, Bi2, B3);
        MERGE3(A1, Ai1, A2, Ai2, A3,
               B1, Bi1, B2, Bi2, B3,
               w1, wi1, w2, wi2, w3);

        idxRow[t] = wi1;
        if (w2 - w1 < MARGIN) {
            if (w3 - w1 < MARGIN) {
                int p = atomicAdd(&sNh, 1);
                heavyRows[p] = t;
            } else {
                int p = atomicAdd(&sNl, 1);
                lightRows[p] = t;
                lightA[p] = wi1;
                lightB[p] = wi2;
            }
        }
    }
    __syncthreads();   // idxRow + light/heavy lists visible

    // ---- light rows: exact fp32 rescore of the 2 in-margin candidates ----
    // (ascending-d fmaf chains identical to the validated vq_fix math; only
    //  512 B of eT per row; all rows in parallel, 2 threads per row.)
    const int nl = sNl;
    const int nh = sNh;
    if (t < 2 * nl) {
        const int j = t >> 1, s = t & 1;
        const int rloc = lightRows[j];
        const int code = s ? lightB[j] : lightA[j];
        const float4* xr = (const float4*)(x + ((size_t)blockIdx.x * 32 + rloc) * 64);
        const float4* er = (const float4*)(eT + (size_t)code * 64);
        float sx = 0.f, dot = 0.f;
        #pragma unroll
        for (int i4 = 0; i4 < 16; ++i4) {
            float4 xv = xr[i4];
            float4 ev = er[i4];
            sx = fmaf(xv.x, xv.x, sx); sx = fmaf(xv.y, xv.y, sx);
            sx = fmaf(xv.z, xv.z, sx); sx = fmaf(xv.w, xv.w, sx);
            dot = fmaf(xv.x, ev.x, dot); dot = fmaf(xv.y, ev.y, dot);
            dot = fmaf(xv.z, ev.z, dot); dot = fmaf(xv.w, ev.w, dot);
        }
        float dd = (sx + sse[code]) - 2.0f * dot;
        // pair exchange (2j, 2j+1 always in wave 0 since nl <= 32)
        float ddo = __shfl_xor(dd, 1, 64);
        int   ido = __shfl_xor(code, 1, 64);
        bool take = (ddo < dd) || (ddo == dd && ido < code);
        int best = take ? ido : code;
        if (s == 0) idxRow[rloc] = best;
    }

    // ---- heavy rows (>=3 candidates in margin, rare): full block rescore ----
    for (int i = 0; i < nh; ++i) {
        const int rloc = heavyRows[i];
        const size_t grow = (size_t)blockIdx.x * 32 + rloc;
        if (t < 64) xs[t] = x[grow * 64 + t];
        __syncthreads();

        float sx = 0.f;
        #pragma unroll
        for (int d = 0; d < 64; ++d) sx = fmaf(xs[d], xs[d], sx);

        const int k0 = t * 2;
        const float4* e0 = (const float4*)(eT + (size_t)(k0 + 0) * 64);
        const float4* e1 = (const float4*)(eT + (size_t)(k0 + 1) * 64);
        float dot0 = 0.f, dot1 = 0.f;
        #pragma unroll
        for (int i4 = 0; i4 < 16; ++i4) {
            float4 v0 = e0[i4], v1 = e1[i4];
            float xa = xs[4 * i4 + 0], xb = xs[4 * i4 + 1];
            float xc = xs[4 * i4 + 2], xd = xs[4 * i4 + 3];
            dot0 = fmaf(xa, v0.x, dot0); dot0 = fmaf(xb, v0.y, dot0);
            dot0 = fmaf(xc, v0.z, dot0); dot0 = fmaf(xd, v0.w, dot0);
            dot1 = fmaf(xa, v1.x, dot1); dot1 = fmaf(xb, v1.y, dot1);
            dot1 = fmaf(xc, v1.z, dot1); dot1 = fmaf(xd, v1.w, dot1);
        }
        float dd0 = (sx + sse[k0 + 0]) - 2.0f * dot0;
        float dd1 = (sx + sse[k0 + 1]) - 2.0f * dot1;
        float db = dd0; int di = k0;
        if (dd1 < db) { db = dd1; di = k0 + 1; }
        cb[t] = db; ci[t] = di;
        __syncthreads();

        if (t < 64) {
            float B = cb[t]; int I = ci[t];
            #pragma unroll
            for (int s = 64; s < 512; s += 64) {
                float b = cb[t + s]; int i2 = ci[t + s];
                bool take = (b < B) || (b == B && i2 < I);
                B = take ? b : B;
                I = take ? i2 : I;
            }
            #pragma unroll
            for (int m = 1; m < 64; m <<= 1) {
                float ob = __shfl_xor(B, m, 64);
                int   oi = __shfl_xor(I, m, 64);
                bool take = (ob < B) || (ob == B && oi < I);
                B = take ? ob : B;
                I = take ? oi : I;
            }
            if (t == 0) idxRow[rloc] = I;
        }
        __syncthreads();   // idxRow patched; xs/cb/ci safe to reuse
    }
    __syncthreads();       // light idxRow writes visible to epilogue

    // ---- epilogue: waves 0-1, lane -> row rowBase+l15 (w==rowGroup here),
    //      elems [quad*16, quad*16+16); per-row math/order unchanged ----
    if (w < 2) {
        const int myidx = idxRow[w * 16 + l15];
        const float4* qrow = (const float4*)(eT + (size_t)myidx * 64 + quad * 16);
        const float4* xrow = (const float4*)(x + (size_t)(rowBase + l15) * 64 + quad * 16);
        float4* orow = (float4*)(out + (size_t)(rowBase + l15) * 64 + quad * 16);
        float lsum = 0.f;
        #pragma unroll
        for (int i = 0; i < 4; ++i) {
            float4 q = qrow[i];
            float4 xv = xrow[i];
            float4 o;
            float dx;
            dx = q.x - xv.x; o.x = xv.x + dx; lsum = fmaf(dx, dx, lsum);
            dx = q.y - xv.y; o.y = xv.y + dx; lsum = fmaf(dx, dx, lsum);
            dx = q.z - xv.z; o.z = xv.z + dx; lsum = fmaf(dx, dx, lsum);
            dx = q.w - xv.w; o.w = xv.w + dx; lsum = fmaf(dx, dx, lsum);
            orow[i] = o;
        }
        #pragma unroll
        for (int off = 32; off > 0; off >>= 1)
            lsum += __shfl_down(lsum, off, 64);
        if (lane == 0) wsum[w] = lsum;
    }
    __syncthreads();

    // ---- plain store of the block partial (NO agent atomics in hot kernel) ----
    if (t == 0) parts[blockIdx.x] = wsum[0] + wsum[1];
}

// ---------------------------------------------------------------------------
// loss finalize: 1 block x 512, plain loads (dispatch boundary = coherence).
// Reduction order replicates R20's validated sum bit-for-bit.
__launch_bounds__(512)
__global__ void vq_loss(const float* __restrict__ parts,
                        float* __restrict__ out) {
    __shared__ float cb[512];
    const int t = threadIdx.x;
    cb[t] = parts[t] + parts[t + 512];
    __syncthreads();
    if (t < 64) {
        float v = cb[t];
        #pragma unroll
        for (int s = 64; s < 512; s += 64) v += cb[t + s];
        #pragma unroll
        for (int off = 32; off > 0; off >>= 1)
            v += __shfl_down(v, off, 64);
        if (t == 0) {
            float m = v / (float)NELEM;
            out[NELEM] = 0.25f * m + m;
        }
    }
}

// ---------------------------------------------------------------------------
extern "C" void kernel_launch(void* const* d_in, const int* in_sizes, int n_in,
                              void* d_out, int out_size, void* d_ws, size_t ws_size,
                              hipStream_t stream) {
    const float* x = (const float*)d_in[0];
    const float* e = (const float*)d_in[1];
    float* out = (float*)d_out;
    float* ws  = (float*)d_ws;

    // ws layout (float offsets):
    //   [0..15]   ctrl (zeroed by prep; unused)
    //   +64       se   [1024]
    //   +1280     eT   [65536]
    //   +66816    ehL  [65536 ushort = 32768 f]  (linear fp16 codebook)
    //   +165120   parts[1024]
    float* se            = ws + 64;
    float* eT            = ws + 1280;
    unsigned short* ehL  = (unsigned short*)(ws + 66816);
    float* parts         = ws + 165120;

    vq_prep<<<64, 256, 0, stream>>>(e, se, eT, ehL, (int*)ws);
    vq_main<<<GRID_MAIN, TPB, 0, stream>>>(x, se, eT, ehL, out, parts);
    vq_loss<<<1, 512, 0, stream>>>(parts, out);
}

// Round 9
// 97.609 us; speedup vs baseline: 2.2226x; 1.4002x over previous
//
#include <hip/hip_runtime.h>
#include <hip/hip_bf16.h>

// VectorQuantizer: x [32768 x 64] fp32, e [64 x 1024] fp32.
// d_out = [out (2097152 f32) = x + (q-x), loss = 1.25*mean((q-x)^2)].
//
// R23 = R19 (best measured: LDS codebook, 256 blk x 1024 thr, main 43.3us,
// total 101.4us) + packed-sortable-key scan. The L2-direct line (R18/R20/R22)
// is abandoned per pre-committed falsification: with spill fixed and memory
// ideal (R22: VGPR 128, FETCH+WRITE 14 MB) it still ran 81us — dependent
// ~200cyc L2 loads can't be covered at 4 waves/SIMD; LDS wins.
// Scan change (cuts the VALU hog, preserves all validated semantics):
//  - key' = se + 32 - 2*dot  (keys in (12,52) > 0: uint order == float order,
//    no sign transform; sse32 staged in LDS so the offset is free).
//  - pack: p = (bits(key') & ~31) | nt  — only 5 bits truncated; each lane
//    scans codes == l15 (mod 16), so nt (0..31) fully identifies the code;
//    full code rebuilt after the loop: code = (nt<<4) + codeBase + l15.
//  - top-3 via 5 integer min/max (indices ride free, earliest-nt tie-break
//    == earliest-code, matching the validated strict-< semantics).
//  - 4 MFMAs chain into ONE accumulator (drops the aA+aB add, -4 VGPR).
// Truncation error <= 32 ulp(52) ~ 1.2e-4 one-sided; budget 8e-4 (fp16 split,
// validated) + 1.2e-4 < MARGIN/2 = 2e-3 -> the flag-safety argument is
// unchanged. Butterfly/merge/light/heavy/epilogue/loss: verbatim R19
// (offsets cancel in every margin difference; rescores are exact fp32).

#define NROWS 32768
#define DDIM  64
#define KCODE 1024
#define NELEM (NROWS * DDIM)
#define MARGIN 4e-3f
#define MAINBLK 256          // 1 block/CU, 1024 threads, 128 rows/block

typedef __attribute__((ext_vector_type(8))) _Float16 f16x8;
typedef __attribute__((ext_vector_type(4))) float f32x4;

static __device__ __forceinline__ unsigned short f2h(float v) {
    _Float16 h = (_Float16)v;
    unsigned short b;
    __builtin_memcpy(&b, &h, 2);
    return b;
}
static __device__ __forceinline__ void gload16(const void* g, void* l) {
    __builtin_amdgcn_global_load_lds(
        (const __attribute__((address_space(1))) void*)g,
        (__attribute__((address_space(3))) void*)l, 16, 0, 0);
}

// ---------------------------------------------------------------------------
// prep (64 blocks x 256): per block 16 codes. se[k] exact fp32 (ascending-d
// fmaf — must match the rescore paths), eT[k][d] fp32, ehSw[k][*] fp16 with
// the 16B-chunk XOR swizzle (chunk ch of code k at slot ch^(k&7)) so the LDS
// image (bit-copied by global_load_lds) serves conflict-free ds_read_b128.
__global__ void vq_prep(const float* __restrict__ e,
                        float* __restrict__ se,
                        float* __restrict__ eT,
                        unsigned short* __restrict__ ehSw,
                        int* __restrict__ ctrl) {
    __shared__ float tile[64][17];
    const int t = threadIdx.x;
    const int k0 = blockIdx.x * 16;
    if (blockIdx.x == 0 && t < 4) ctrl[t] = 0;
    #pragma unroll
    for (int i = 0; i < 4; ++i) {
        int idx = i * 256 + t;
        int d = idx >> 4, kk = idx & 15;
        tile[d][kk] = e[d * KCODE + k0 + kk];
    }
    __syncthreads();
    if (t < 16) {
        float s = 0.f;
        #pragma unroll
        for (int d = 0; d < 64; ++d) { float v = tile[d][t]; s = fmaf(v, v, s); }
        se[k0 + t] = s;
    }
    const int kk = t >> 4;            // code 0..15 within block
    const int dg = (t & 15) * 4;      // dim group (4 elems)
    const int kg = k0 + kk;
    float v0 = tile[dg + 0][kk], v1 = tile[dg + 1][kk];
    float v2 = tile[dg + 2][kk], v3 = tile[dg + 3][kk];
    *(float4*)&eT[(size_t)kg * 64 + dg] = make_float4(v0, v1, v2, v3);
    const int sw = (((dg >> 3) ^ (kg & 7)) << 3) + (dg & 7);
    *(ushort4*)&ehSw[(size_t)kg * 64 + sw] =
        make_ushort4(f2h(v0), f2h(v1), f2h(v2), f2h(v3));
}

// ---------------------------------------------------------------------------
__launch_bounds__(1024)
__global__ void vq_main(const float* __restrict__ x,
                        const float* __restrict__ se,
                        const float* __restrict__ eT,
                        const unsigned short* __restrict__ ehSw,
                        float* __restrict__ out,
                        float* __restrict__ parts) {
    __shared__ unsigned short Beh[KCODE * 64];   // 128 KB, swizzled fp16 codebook
    __shared__ float sse[KCODE];                 // 4 KB (exact fp32 se copy)
    __shared__ float sse32[KCODE];               // 4 KB (se + 32, scan offset)
    __shared__ float wsum[8];
    __shared__ float xs[64];                     // heavy rescore: current row
    __shared__ float cb[1024];                   // heavy reduction
    __shared__ int   ci[1024];
    __shared__ float hv1[2][128], hv2[2][128], hv3[2][128];   // per-half top-3
    __shared__ int   hi1[2][128], hi2[2][128];                // per-half top-2 idx
    __shared__ int   lightRows[128];             // block-relative light rows
    __shared__ int   lightA[128];                // light candidate 1 (si)
    __shared__ int   lightB[128];                // light candidate 2 (si2)
    __shared__ int   heavyRows[128];             // >=3 candidates in margin
    __shared__ int   idxRow[128];                // per-row final code index
    __shared__ int   sNl, sNh;

    const int t = threadIdx.x;          // 0..1023
    const int lane = t & 63;
    const int w = t >> 6;               // wave 0..15
    const int w8 = w & 7;               // row-group 0..7
    const int half = w >> 3;            // code half 0/1
    const int quad = lane >> 4, l15 = lane & 15;
    const int rowBase = blockIdx.x * 128 + w8 * 16;  // wave pair owns 16 rows

    if (t == 0) { sNl = 0; sNh = 0; }

    // ---- stage codebook (bit-copy of the swizzled global image) + se ----
    {
        const unsigned char* g = (const unsigned char*)ehSw;
        #pragma unroll
        for (int r = 0; r < 8; ++r)
            gload16(g + (size_t)(r * 1024 + t) * 16, &Beh[(r * 1024 + t) * 8]);
        float s = se[t];
        sse[t] = s;
        sse32[t] = s + 32.0f;
    }

    // ---- A fragments (fp16 two-term split): row = l15, k = quad*8+ks*32+j ----
    f16x8 ah0, ah1, al0, al1;
    {
        const float4* ap0 = (const float4*)(x + (size_t)(rowBase + l15) * 64 + quad * 8);
        const float4* ap1 = (const float4*)(x + (size_t)(rowBase + l15) * 64 + 32 + quad * 8);
        float4 a0 = ap0[0], a1 = ap0[1], b0 = ap1[0], b1 = ap1[1];
        float av[8] = {a0.x, a0.y, a0.z, a0.w, a1.x, a1.y, a1.z, a1.w};
        float bv[8] = {b0.x, b0.y, b0.z, b0.w, b1.x, b1.y, b1.z, b1.w};
        f16x8 h0, h1, l0, l1;
        #pragma unroll
        for (int j = 0; j < 8; ++j) {
            _Float16 ha = (_Float16)av[j];
            _Float16 hb = (_Float16)bv[j];
            h0[j] = ha;
            h1[j] = hb;
            l0[j] = (_Float16)(av[j] - (float)ha);
            l1[j] = (_Float16)(bv[j] - (float)hb);
        }
        ah0 = h0; ah1 = h1; al0 = l0; al1 = l1;
    }
    __syncthreads();   // codebook + se + counters resident; drains gload16 vmcnt

    // ---- barrier-free half-scan: 32 iters x 16 codes, all from LDS ----
    // packed sortable keys: p = (bits(se+32-2dot) & ~31) | nt ; integer top-3.
    unsigned pk1[4], pk2[4], pk3[4];
    #pragma unroll
    for (int r = 0; r < 4; ++r) { pk1[r] = 0xFFFFFFFFu; pk2[r] = 0xFFFFFFFFu; pk3[r] = 0xFFFFFFFFu; }

    const int slot0 = ((quad ^ (l15 & 7)) << 3);        // ks=0 chunk (elems)
    const int slot1 = (((quad + 4) ^ (l15 & 7)) << 3);  // ks=1 chunk
    const int codeBase = half * 512;
    const int base_l = codeBase + l15;                  // for post-loop unpack

    #pragma unroll 4
    for (int nt = 0; nt < 32; ++nt) {
        const int code = codeBase + nt * 16 + l15;
        f16x8 b0 = *(const f16x8*)&Beh[code * 64 + slot0];
        f16x8 b1 = *(const f16x8*)&Beh[code * 64 + slot1];
        float cse32 = sse32[code];
        f32x4 aA = {0.f, 0.f, 0.f, 0.f};
        aA = __builtin_amdgcn_mfma_f32_16x16x32_f16(ah0, b0, aA, 0, 0, 0);
        aA = __builtin_amdgcn_mfma_f32_16x16x32_f16(ah1, b1, aA, 0, 0, 0);
        aA = __builtin_amdgcn_mfma_f32_16x16x32_f16(al0, b0, aA, 0, 0, 0);
        aA = __builtin_amdgcn_mfma_f32_16x16x32_f16(al1, b1, aA, 0, 0, 0);
        #pragma unroll
        for (int r = 0; r < 4; ++r) {
            float key = fmaf(-2.f, aA[r], cse32);   // in (12,52): positive
            unsigned p = (__float_as_uint(key) & 0xFFFFFFE0u) | (unsigned)nt;
            unsigned h1 = max(p, pk1[r]);
            pk1[r]      = min(p, pk1[r]);
            unsigned h2 = max(h1, pk2[r]);
            pk2[r]      = min(h1, pk2[r]);
            pk3[r]      = min(h2, pk3[r]);
        }
    }

    // ---- unpack to (float, code) — offsets cancel in all margin diffs ----
    float sb[4], sb2[4], sb3[4];
    int   si[4], si2[4];
    #pragma unroll
    for (int r = 0; r < 4; ++r) {
        sb[r]  = __uint_as_float(pk1[r] & 0xFFFFFFE0u);
        si[r]  = (int)((pk1[r] & 31u) << 4) + base_l;
        sb2[r] = __uint_as_float(pk2[r] & 0xFFFFFFE0u);
        si2[r] = (int)((pk2[r] & 31u) << 4) + base_l;
        sb3[r] = __uint_as_float(pk3[r] & 0xFFFFFFE0u);
    }

    // ---- in-wave butterfly top-3 merge over the 16 lanes of each quad ----
    #pragma unroll
    for (int m = 1; m < 16; m <<= 1) {
        #pragma unroll
        for (int r = 0; r < 4; ++r) {
            float b1 = __shfl_xor(sb[r],  m, 64);
            int   i1 = __shfl_xor(si[r],  m, 64);
            float b2 = __shfl_xor(sb2[r], m, 64);
            int   i2 = __shfl_xor(si2[r], m, 64);
            float b3 = __shfl_xor(sb3[r], m, 64);
            // round 1: champion (lexicographic (value, index))
            bool t1 = (b1 < sb[r]) || (b1 == sb[r] && i1 < si[r]);
            float w1 = t1 ? b1 : sb[r];    int wi1 = t1 ? i1 : si[r];
            float l1 = t1 ? sb[r] : b1;    int li1 = t1 ? si[r] : i1;
            float c2 = t1 ? b2 : sb2[r];   int ci2 = t1 ? i2 : si2[r];   // winner side's 2nd
            float c3 = t1 ? b3 : sb3[r];                                  // winner side's 3rd
            float o2 = t1 ? sb2[r] : b2;                                  // loser side's 2nd
            // round 2: second place
            bool t2 = (c2 < l1) || (c2 == l1 && ci2 < li1);
            float w2 = t2 ? c2 : l1;       int wi2 = t2 ? ci2 : li1;
            // third place (value only; used only for the margin test)
            float w3 = t2 ? fminf(l1, c3) : fminf(c2, o2);
            sb[r] = w1; si[r] = wi1; sb2[r] = w2; si2[r] = wi2; sb3[r] = w3;
        }
    }

    // ---- publish this half's per-row top-3 to LDS ----
    if (l15 == 0) {
        #pragma unroll
        for (int r = 0; r < 4; ++r) {
            const int rloc = w8 * 16 + quad * 4 + r;
            hv1[half][rloc] = sb[r];  hi1[half][rloc] = si[r];
            hv2[half][rloc] = sb2[r]; hi2[half][rloc] = si2[r];
            hv3[half][rloc] = sb3[r];
        }
    }
    __syncthreads();   // both halves published

    // ---- merge halves per row + classify (light/heavy); same lex compare ----
    if (t < 128) {
        float a1 = hv1[0][t]; int ai1 = hi1[0][t];
        float a2 = hv2[0][t]; int ai2 = hi2[0][t];
        float a3 = hv3[0][t];
        float b1 = hv1[1][t]; int bi1 = hi1[1][t];
        float b2 = hv2[1][t]; int bi2 = hi2[1][t];
        float b3 = hv3[1][t];
        bool t1 = (b1 < a1) || (b1 == a1 && bi1 < ai1);
        float w1 = t1 ? b1 : a1;   int wi1 = t1 ? bi1 : ai1;
        float l1 = t1 ? a1 : b1;   int li1 = t1 ? ai1 : bi1;
        float c2 = t1 ? b2 : a2;   int ci2 = t1 ? bi2 : ai2;
        float c3 = t1 ? b3 : a3;
        float o2 = t1 ? a2 : b2;
        bool t2 = (c2 < l1) || (c2 == l1 && ci2 < li1);
        float w2 = t2 ? c2 : l1;   int wi2 = t2 ? ci2 : li1;
        float w3 = t2 ? fminf(l1, c3) : fminf(c2, o2);

        idxRow[t] = wi1;
        if (w2 - w1 < MARGIN) {
            if (w3 - w1 < MARGIN) {
                int p = atomicAdd(&sNh, 1);
                heavyRows[p] = t;
            } else {
                int p = atomicAdd(&sNl, 1);
                lightRows[p] = t;
                lightA[p] = wi1;
                lightB[p] = wi2;
            }
        }
    }
    __syncthreads();   // idxRow + light/heavy lists visible

    // ---- light rows: exact fp32 rescore of the 2 in-margin candidates ----
    // (ascending-d fmaf chains identical to the validated vq_fix math; only
    //  512 B of eT per row; all rows in parallel, 2 threads per row.)
    const int nl = sNl;
    const int nh = sNh;
    if (t < 2 * nl) {
        const int j = t >> 1, s = t & 1;
        const int rloc = lightRows[j];
        const int code = s ? lightB[j] : lightA[j];
        const float4* xr = (const float4*)(x + ((size_t)blockIdx.x * 128 + rloc) * 64);
        const float4* er = (const float4*)(eT + (size_t)code * 64);
        float sx = 0.f, dot = 0.f;
        #pragma unroll
        for (int i4 = 0; i4 < 16; ++i4) {
            float4 xv = xr[i4];
            float4 ev = er[i4];
            sx = fmaf(xv.x, xv.x, sx); sx = fmaf(xv.y, xv.y, sx);
            sx = fmaf(xv.z, xv.z, sx); sx = fmaf(xv.w, xv.w, sx);
            dot = fmaf(xv.x, ev.x, dot); dot = fmaf(xv.y, ev.y, dot);
            dot = fmaf(xv.z, ev.z, dot); dot = fmaf(xv.w, ev.w, dot);
        }
        float dd = (sx + sse[code]) - 2.0f * dot;
        // pair exchange (2j, 2j+1 always in the same wave)
        float ddo = __shfl_xor(dd, 1, 64);
        int   ido = __shfl_xor(code, 1, 64);
        bool take = (ddo < dd) || (ddo == dd && ido < code);
        int best = take ? ido : code;
        if (s == 0) idxRow[rloc] = best;
    }

    // ---- heavy rows (>=3 candidates in margin, rare): full block rescore ----
    for (int i = 0; i < nh; ++i) {
        const int rloc = heavyRows[i];
        const size_t grow = (size_t)blockIdx.x * 128 + rloc;
        if (t < 64) xs[t] = x[grow * 64 + t];
        __syncthreads();

        float sx = 0.f;
        #pragma unroll
        for (int d = 0; d < 64; ++d) sx = fmaf(xs[d], xs[d], sx);

        // one code per thread; per-code fmaf chain identical to vq_fix
        const float4* e0 = (const float4*)(eT + (size_t)t * 64);
        float dot0 = 0.f;
        #pragma unroll
        for (int i4 = 0; i4 < 16; ++i4) {
            float4 v0 = e0[i4];
            float xa = xs[4 * i4 + 0], xb = xs[4 * i4 + 1];
            float xc = xs[4 * i4 + 2], xd = xs[4 * i4 + 3];
            dot0 = fmaf(xa, v0.x, dot0); dot0 = fmaf(xb, v0.y, dot0);
            dot0 = fmaf(xc, v0.z, dot0); dot0 = fmaf(xd, v0.w, dot0);
        }
        float dd0 = (sx + sse[t]) - 2.0f * dot0;
        cb[t] = dd0; ci[t] = t;
        __syncthreads();

        if (t < 64) {
            float B = cb[t]; int I = ci[t];
            #pragma unroll
            for (int s = 64; s < 1024; s += 64) {
                float b = cb[t + s]; int i2 = ci[t + s];
                bool take = (b < B) || (b == B && i2 < I);
                B = take ? b : B;
                I = take ? i2 : I;
            }
            #pragma unroll
            for (int m = 1; m < 64; m <<= 1) {
                float ob = __shfl_xor(B, m, 64);
                int   oi = __shfl_xor(I, m, 64);
                bool take = (ob < B) || (ob == B && oi < I);
                B = take ? ob : B;
                I = take ? oi : I;
            }
            if (t == 0) idxRow[rloc] = I;
        }
        __syncthreads();   // idxRow patched; xs/cb/ci safe to reuse
    }
    __syncthreads();       // light idxRow writes visible to epilogue

    // ---- epilogue: waves 0-7 only (identical mapping + reduction order to
    //      prior validated rounds so the loss bits are unchanged) ----
    if (w < 8) {
        const int myidx = idxRow[w * 16 + l15];
        const float4* qrow = (const float4*)(eT + (size_t)myidx * 64 + quad * 16);
        const float4* xrow = (const float4*)(x + (size_t)(rowBase + l15) * 64 + quad * 16);
        float4* orow = (float4*)(out + (size_t)(rowBase + l15) * 64 + quad * 16);
        float lsum = 0.f;
        #pragma unroll
        for (int i = 0; i < 4; ++i) {
            float4 q = qrow[i];
            float4 xv = xrow[i];
            float4 o;
            float dx;
            dx = q.x - xv.x; o.x = xv.x + dx; lsum = fmaf(dx, dx, lsum);
            dx = q.y - xv.y; o.y = xv.y + dx; lsum = fmaf(dx, dx, lsum);
            dx = q.z - xv.z; o.z = xv.z + dx; lsum = fmaf(dx, dx, lsum);
            dx = q.w - xv.w; o.w = xv.w + dx; lsum = fmaf(dx, dx, lsum);
            orow[i] = o;
        }
        #pragma unroll
        for (int off = 32; off > 0; off >>= 1)
            lsum += __shfl_down(lsum, off, 64);
        if (lane == 0) wsum[w] = lsum;
    }
    __syncthreads();

    // ---- plain store of the block partial (NO agent atomics in hot kernel) ----
    if (t == 0) {
        float s = 0.f;
        #pragma unroll
        for (int i = 0; i < 8; ++i) s += wsum[i];
        parts[blockIdx.x] = s;
    }
}

// ---------------------------------------------------------------------------
// loss finalize: 1 block x 256, plain loads (dispatch boundary = coherence).
// Reduction order replicates R0's validated last-block sum bit-for-bit.
__launch_bounds__(256)
__global__ void vq_loss(const float* __restrict__ parts,
                        float* __restrict__ out) {
    __shared__ float cb[256];
    const int t = threadIdx.x;
    cb[t] = parts[t];
    __syncthreads();
    if (t < 64) {
        float v = cb[t] + cb[t + 64] + cb[t + 128] + cb[t + 192];
        #pragma unroll
        for (int off = 32; off > 0; off >>= 1)
            v += __shfl_down(v, off, 64);
        if (t == 0) {
            float m = v / (float)NELEM;
            out[NELEM] = 0.25f * m + m;
        }
    }
}

// ---------------------------------------------------------------------------
extern "C" void kernel_launch(void* const* d_in, const int* in_sizes, int n_in,
                              void* d_out, int out_size, void* d_ws, size_t ws_size,
                              hipStream_t stream) {
    const float* x = (const float*)d_in[0];
    const float* e = (const float*)d_in[1];
    float* out = (float*)d_out;
    float* ws  = (float*)d_ws;

    // ws layout (float offsets):
    //   [0..15]   ctrl (zeroed by prep; unused)
    //   +64       se   [1024]
    //   +1280     eT   [65536]
    //   +66816    ehSw [65536 ushort = 32768 f]  (swizzled fp16, LDS image)
    //   +165120   parts[256]
    float* se            = ws + 64;
    float* eT            = ws + 1280;
    unsigned short* ehSw = (unsigned short*)(ws + 66816);
    float* parts         = ws + 165120;

    vq_prep<<<64, 256, 0, stream>>>(e, se, eT, ehSw, (int*)ws);
    vq_main<<<MAINBLK, 1024, 0, stream>>>(x, se, eT, ehSw, out, parts);
    vq_loss<<<1, 256, 0, stream>>>(parts, out);
}